// Round 10
// baseline (12602.985 us; speedup 1.0000x reference)
//
#include <hip/hip_runtime.h>
#include <hip/hip_cooperative_groups.h>

namespace cg = cooperative_groups;

#define NF 64
#define NC 40

typedef _Float16 half1;
typedef _Float16 half4 __attribute__((ext_vector_type(4)));
typedef _Float16 half8 __attribute__((ext_vector_type(8)));
typedef float    f32x4 __attribute__((ext_vector_type(4)));
typedef float    f32x8 __attribute__((ext_vector_type(8)));

// ---------- setup kernels (run once per call) ----------

__global__ void k_deg(const int* __restrict__ row, int* __restrict__ deg_cnt, int E) {
    int stride = gridDim.x * blockDim.x;
    for (int e = blockIdx.x * blockDim.x + threadIdx.x; e < E; e += stride)
        atomicAdd(&deg_cnt[row[e]], 1);
}

__global__ void k_node(const float* __restrict__ x, const int* __restrict__ y,
                       const int* __restrict__ mask, int* __restrict__ ylab,
                       int* __restrict__ cls_cnt, float* __restrict__ mean_sum, int N) {
    __shared__ float lmean[NF];
    __shared__ int   lcls[NC];
    int t = threadIdx.x;
    if (t < NF) lmean[t] = 0.f;
    if (t < NC) lcls[t]  = 0;
    __syncthreads();
    int stride = gridDim.x * blockDim.x;
    const float4* x4 = (const float4*)x;
    int total4 = N * 16;
    f32x4 acc = {0.f, 0.f, 0.f, 0.f};
    for (int i = blockIdx.x * blockDim.x + t; i < total4; i += stride) {
        float4 v = x4[i];
        acc.x += v.x; acc.y += v.y; acc.z += v.z; acc.w += v.w;
    }
    int cbase = (t & 15) * 4;
    atomicAdd(&lmean[cbase + 0], acc.x);
    atomicAdd(&lmean[cbase + 1], acc.y);
    atomicAdd(&lmean[cbase + 2], acc.z);
    atomicAdd(&lmean[cbase + 3], acc.w);
    for (int i = blockIdx.x * blockDim.x + t; i < N; i += stride) {
        int lab = (mask[i] > 0) ? y[i] : -1;
        ylab[i] = lab;
        if (lab >= 0) atomicAdd(&lcls[lab], 1);
    }
    __syncthreads();
    if (t < NF) atomicAdd(&mean_sum[t], lmean[t]);
    if (t < NC) atomicAdd(&cls_cnt[t], lcls[t]);
}

// hierarchical scan of deg_cnt (N % 4 == 0; N=50000 -> n4=12500)
__global__ void __launch_bounds__(256) k_blocksum(const int* __restrict__ deg_cnt,
                                                  int* __restrict__ bsum, int n4) {
    __shared__ int red[256];
    int idx4 = blockIdx.x * 256 + threadIdx.x;
    int s = 0;
    if (idx4 < n4) {
        int4 d = ((const int4*)deg_cnt)[idx4];
        s = d.x + d.y + d.z + d.w;
    }
    red[threadIdx.x] = s;
    __syncthreads();
    for (int off = 128; off > 0; off >>= 1) {
        if (threadIdx.x < off) red[threadIdx.x] += red[threadIdx.x + off];
        __syncthreads();
    }
    if (threadIdx.x == 0) bsum[blockIdx.x] = red[0];
}

__global__ void k_scanmeta(const int* __restrict__ bsum, int* __restrict__ bpre, int NB,
                           int* __restrict__ row_ptr_last,
                           const int* __restrict__ cls_cnt, int* __restrict__ cls_ptr,
                           float* __restrict__ inv_cnt,
                           const float* __restrict__ mean_sum, float* __restrict__ meanv,
                           int N) {
    __shared__ int lds[256];
    int t = threadIdx.x;
    int v = (t < NB) ? bsum[t] : 0;
    lds[t] = v;
    __syncthreads();
    for (int off = 1; off < 256; off <<= 1) {
        int u = (t >= off) ? lds[t - off] : 0;
        __syncthreads();
        lds[t] += u;
        __syncthreads();
    }
    if (t < NB) bpre[t] = lds[t] - v;
    if (t == 255) *row_ptr_last = lds[255];
    if (t < NF) meanv[t] = mean_sum[t] * (1.f / (float)N);
    if (t == 0) {
        int s2 = 0;
        for (int c = 0; c < NC; ++c) {
            cls_ptr[c] = s2;
            int cc = cls_cnt[c];
            s2 += cc;
            inv_cnt[c] = 1.f / ((float)cc + 1e-8f);
        }
        cls_ptr[NC] = s2;
    }
}

__global__ void __launch_bounds__(256) k_fillptr(const int* __restrict__ deg_cnt,
                                                 const int* __restrict__ bpre,
                                                 int* __restrict__ row_ptr,
                                                 float* __restrict__ inv_deg, int n4) {
    __shared__ int lds[256];
    int t = threadIdx.x;
    int idx4 = blockIdx.x * 256 + t;
    int4 d = {0, 0, 0, 0};
    if (idx4 < n4) d = ((const int4*)deg_cnt)[idx4];
    int s = d.x + d.y + d.z + d.w;
    lds[t] = s;
    __syncthreads();
    for (int off = 1; off < 256; off <<= 1) {
        int u = (t >= off) ? lds[t - off] : 0;
        __syncthreads();
        lds[t] += u;
        __syncthreads();
    }
    if (idx4 < n4) {
        int base = bpre[blockIdx.x] + lds[t] - s;
        int4 rp;
        rp.x = base;
        rp.y = rp.x + d.x;
        rp.z = rp.y + d.y;
        rp.w = rp.z + d.z;
        ((int4*)row_ptr)[idx4] = rp;
        float4 id;
        id.x = 1.f / (float)(d.x + 1);
        id.y = 1.f / (float)(d.y + 1);
        id.z = 1.f / (float)(d.z + 1);
        id.w = 1.f / (float)(d.w + 1);
        ((float4*)inv_deg)[idx4] = id;
    }
}

// deg_cnt consumed as a countdown (re-zeroed by next call's memset).
__global__ void k_fill(const int* __restrict__ row, const int* __restrict__ col,
                       const int* __restrict__ row_ptr, int* __restrict__ deg_cnt,
                       int* __restrict__ csr_col, const int* __restrict__ ylab,
                       const int* __restrict__ cls_ptr, int* __restrict__ cls_fill,
                       int* __restrict__ cls_nodes, int N, int E) {
    int stride = gridDim.x * blockDim.x;
    for (int e = blockIdx.x * blockDim.x + threadIdx.x; e < E; e += stride) {
        int r = row[e];
        int d = atomicSub(&deg_cnt[r], 1);
        csr_col[row_ptr[r] + d - 1] = col[e];
    }
    for (int i = blockIdx.x * blockDim.x + threadIdx.x; i < N; i += stride) {
        int lab = ylab[i];
        if (lab >= 0) {
            int pos = cls_ptr[lab] + atomicAdd(&cls_fill[lab], 1);
            cls_nodes[pos] = i;
        }
    }
}

// v0h = xch = fp16(x - mean)
__global__ void k_init(const float* __restrict__ x, const float* __restrict__ meanv,
                       half1* __restrict__ v0h, half1* __restrict__ xch, int N) {
    int total = N * 16;                      // half4 count
    int stride = gridDim.x * blockDim.x;
    const float4* x4 = (const float4*)x;
    const float4* m4 = (const float4*)meanv;
    for (int idx = blockIdx.x * blockDim.x + threadIdx.x; idx < total; idx += stride) {
        float4 xv = x4[idx];
        float4 mv = m4[idx & 15];
        half4 h;
        h.x = (half1)(xv.x - mv.x);
        h.y = (half1)(xv.y - mv.y);
        h.z = (half1)(xv.z - mv.z);
        h.w = (half1)(xv.w - mv.w);
        ((half4*)v0h)[idx] = h;
        ((half4*)xch)[idx] = h;
    }
}

// seed yTv[0] = Y^T v_0  (runs once before the iteration loop)
__global__ void __launch_bounds__(256) k_accum(const half1* __restrict__ v,
                                               const int* __restrict__ cls_ptr,
                                               const int* __restrict__ cls_nodes,
                                               float* __restrict__ yTv) {
    __shared__ float red[4 * NF];
    int c = blockIdx.x;
    int lane = threadIdx.x & 63;
    int w = threadIdx.x >> 6;
    int g = lane >> 4, q = lane & 15;
    int W = blockIdx.y * 4 + w;
    int cs = cls_ptr[c], ce = cls_ptr[c + 1];
    const half4* v4 = (const half4*)v;
    f32x4 acc = {0.f, 0.f, 0.f, 0.f};
    for (int p = cs + W * 4 + g; p < ce; p += 64 * 4) {
        int node = cls_nodes[p];
        acc += __builtin_convertvector(v4[(long)node * 16 + q], f32x4);
    }
#pragma unroll
    for (int m = 16; m <= 32; m <<= 1) {
        acc.x += __shfl_xor(acc.x, m);
        acc.y += __shfl_xor(acc.y, m);
        acc.z += __shfl_xor(acc.z, m);
        acc.w += __shfl_xor(acc.w, m);
    }
    if (g == 0) {
        red[w * NF + q * 4 + 0] = acc.x;
        red[w * NF + q * 4 + 1] = acc.y;
        red[w * NF + q * 4 + 2] = acc.z;
        red[w * NF + q * 4 + 3] = acc.w;
    }
    __syncthreads();
    if (w == 0) {
        float s = red[0 * NF + lane] + red[1 * NF + lane] +
                  red[2 * NF + lane] + red[3 * NF + lane];
        atomicAdd(&yTv[c * NF + lane], s);
    }
}

// ---------- per-iteration kernel (fallback path, known-good R8) ----------
__global__ void __launch_bounds__(256) k_combine(
        const half1* __restrict__ v, half1* __restrict__ vn,
        const half1* __restrict__ xch, const float* __restrict__ inv_deg,
        const int* __restrict__ row_ptr, const int* __restrict__ csr_col,
        const int* __restrict__ ylab, const float* __restrict__ yv_cur,
        const float* __restrict__ inv_cnt, float* __restrict__ yv_acc,
        float* __restrict__ yv_zero, int N) {
    int lane = threadIdx.x & 63;
    int w = threadIdx.x >> 6;
    int i = blockIdx.x * 4 + w;
    if (blockIdx.x == 0) {
        for (int j = threadIdx.x; j < NC * NF; j += 256) yv_zero[j] = 0.f;
    }
    if (i >= N) return;
    int s = row_ptr[i], e = row_ptr[i + 1];
    int g = lane >> 3, q = lane & 7;
    const half8* v8 = (const half8*)v;
    f32x8 a0 = {0.f, 0.f, 0.f, 0.f, 0.f, 0.f, 0.f, 0.f};
    f32x8 a1 = {0.f, 0.f, 0.f, 0.f, 0.f, 0.f, 0.f, 0.f};
    int p = s + g;
    for (; p + 8 < e; p += 16) {
        int c0 = csr_col[p];
        int c1 = csr_col[p + 8];
        half8 h0 = v8[(long)c0 * 8 + q];
        half8 h1 = v8[(long)c1 * 8 + q];
        a0 += __builtin_convertvector(h0, f32x8);
        a1 += __builtin_convertvector(h1, f32x8);
    }
    if (p < e) {
        int c0 = csr_col[p];
        a0 += __builtin_convertvector(v8[(long)c0 * 8 + q], f32x8);
    }
    a0 += a1;
#pragma unroll
    for (int m = 8; m <= 32; m <<= 1) {
#pragma unroll
        for (int j = 0; j < 8; ++j)
            a0[j] += __shfl_xor(a0[j], m);
    }
    int f = q * 8 + g;
    float gsum = a0[g];
    float selfv = (float)v[(long)i * NF + f];
    float p1 = inv_deg[i] * (gsum + selfv);
    int lab = ylab[i];
    float p2 = (lab >= 0) ? yv_cur[lab * NF + f] * inv_cnt[lab] : 0.f;
    float base = (float)xch[(long)i * NF + f];
    float res = 0.45f * p1 + 0.05f * p2 + 0.5f * base;
    vn[(long)i * NF + f] = (half1)res;
    if (lab >= 0) atomicAdd(&yv_acc[lab * NF + f], res);
}

// ---------- persistent cooperative kernel (primary path) ----------
// All 50 iterations in one dispatch with grid.sync() between them.
// Grid MUST be fully co-resident: 1024 blocks @ __launch_bounds__(256,4)
// (4 blocks/CU guaranteed; R9 lesson: 1536@(256,6) was rejected at launch —
// always keep cooperative grids under the conservative occupancy bound and
// CHECK the launch result).
__global__ void __launch_bounds__(256, 4) k_persist(
        half1* __restrict__ va, half1* __restrict__ vb,
        const half1* __restrict__ xch, const float* __restrict__ inv_deg,
        const int* __restrict__ row_ptr, const int* __restrict__ csr_col,
        const int* __restrict__ ylab, const float* __restrict__ inv_cnt,
        float* yv0, float* yv1, float* yv2, int N, int niter) {
    cg::grid_group gg = cg::this_grid();
    int lane = threadIdx.x & 63;
    int w = threadIdx.x >> 6;
    int gw = blockIdx.x * 4 + w;             // global wave id
    int nw = gridDim.x * 4;                  // total waves
    int g = lane >> 3, q = lane & 7;         // 8 streams x 8 lanes (16B each)
    int f = q * 8 + g;                       // feature this lane finalizes

    const half1* vc = va;
    half1*       vn = vb;
    float* ycur = yv0;                       // read this iter
    float* yacc = yv1;                       // accumulate this iter
    float* yzer = yv2;                       // zero this iter (used in t+2)

    for (int t = 0; t < niter; ++t) {
        if (blockIdx.x == 0) {               // zero via coherence-point writes
            for (int j = threadIdx.x; j < NC * NF; j += 256)
                atomicExch(&yzer[j], 0.f);
        }
        const half8* v8 = (const half8*)vc;
        for (int i = gw; i < N; i += nw) {
            int s = row_ptr[i], e = row_ptr[i + 1];
            f32x8 a0 = {0.f, 0.f, 0.f, 0.f, 0.f, 0.f, 0.f, 0.f};
            f32x8 a1 = {0.f, 0.f, 0.f, 0.f, 0.f, 0.f, 0.f, 0.f};
            int p = s + g;
            for (; p + 8 < e; p += 16) {
                int c0 = csr_col[p];
                int c1 = csr_col[p + 8];
                half8 h0 = v8[(long)c0 * 8 + q];
                half8 h1 = v8[(long)c1 * 8 + q];
                a0 += __builtin_convertvector(h0, f32x8);
                a1 += __builtin_convertvector(h1, f32x8);
            }
            if (p < e) {
                int c0 = csr_col[p];
                a0 += __builtin_convertvector(v8[(long)c0 * 8 + q], f32x8);
            }
            a0 += a1;
#pragma unroll
            for (int m = 8; m <= 32; m <<= 1) {
#pragma unroll
                for (int j = 0; j < 8; ++j)
                    a0[j] += __shfl_xor(a0[j], m);
            }
            float gsum = a0[g];
            float selfv = (float)vc[(long)i * NF + f];
            float p1 = inv_deg[i] * (gsum + selfv);
            int lab = ylab[i];
            float p2 = (lab >= 0) ? ycur[lab * NF + f] * inv_cnt[lab] : 0.f;
            float base = (float)xch[(long)i * NF + f];
            float res = 0.45f * p1 + 0.05f * p2 + 0.5f * base;
            vn[(long)i * NF + f] = (half1)res;
            if (lab >= 0) atomicAdd(&yacc[lab * NF + f], res);
        }
        __threadfence();                     // agent-scope release (wb L2)
        gg.sync();                           // grid barrier + acquire
        { const half1* tv = vc; vc = vn; vn = (half1*)tv; }
        { float* ty = ycur; ycur = yacc; yacc = yzer; yzer = ty; }
    }
}

// out = v @ W + bias  (reads fp16 v from ws, writes f32 to d_out)
__global__ void __launch_bounds__(256) k_out(const half1* __restrict__ v,
                                             const float* __restrict__ Wm,
                                             const float* __restrict__ bias,
                                             float* __restrict__ out, int N) {
    __shared__ float Wl[NF * NF];
    for (int j = threadIdx.x; j < NF * NF; j += 256) Wl[j] = Wm[j];
    __syncthreads();
    int lane = threadIdx.x & 63;
    int w = threadIdx.x >> 6;
    int i = blockIdx.x * 4 + w;
    if (i >= N) return;
    float vr = (float)v[(long)i * NF + lane];
    float acc = bias[lane];
#pragma unroll
    for (int k = 0; k < NF; ++k)
        acc += __shfl(vr, k, 64) * Wl[k * NF + lane];
    out[(long)i * NF + lane] = acc;
}

// ---------- launcher ----------

extern "C" void kernel_launch(void* const* d_in, const int* in_sizes, int n_in,
                              void* d_out, int out_size, void* d_ws, size_t ws_size,
                              hipStream_t stream) {
    const float* x      = (const float*)d_in[0];
    const float* weight = (const float*)d_in[1];
    const float* bias   = (const float*)d_in[2];
    const int*   row    = (const int*)d_in[3];
    const int*   col    = (const int*)d_in[4];
    const int*   y      = (const int*)d_in[5];
    const int*   mask   = (const int*)d_in[6];
    int N = in_sizes[0] / NF;
    int E = in_sizes[3];
    int n4 = N / 4;
    int NB = (n4 + 255) / 256;

    char* ws = (char*)d_ws;
    size_t off = 0;
    auto alloc = [&](size_t bytes) -> void* {
        void* p = ws + off;
        off = (off + bytes + 255) & ~(size_t)255;
        return p;
    };
    half1* v0h       = (half1*)alloc((size_t)N * NF * 2);   // 6.4 MB
    half1* v1h       = (half1*)alloc((size_t)N * NF * 2);   // 6.4 MB
    // zero region (one memset per call)
    char*  zbase     = ws + off;
    float* yv0       = (float*)alloc(NC * NF * 4);
    float* yv1       = (float*)alloc(NC * NF * 4);
    float* yv2       = (float*)alloc(NC * NF * 4);
    int*   deg_cnt   = (int*)  alloc((size_t)N * 4);
    int*   cls_cnt   = (int*)  alloc(NC * 4);
    int*   cls_fill  = (int*)  alloc(NC * 4);
    float* mean_sum  = (float*)alloc(NF * 4);
    size_t zbytes = (size_t)((ws + off) - zbase);
    // setup-written, iteration-read
    float* meanv     = (float*)alloc(NF * 4);
    float* inv_deg   = (float*)alloc((size_t)N * 4);
    int*   row_ptr   = (int*)  alloc((size_t)(N + 1) * 4);
    int*   cls_ptr   = (int*)  alloc((NC + 1) * 4);
    float* inv_cnt   = (float*)alloc(NC * 4);
    int*   ylab      = (int*)  alloc((size_t)N * 4);
    int*   cls_nodes = (int*)  alloc((size_t)N * 4);
    int*   bsum      = (int*)  alloc(256 * 4);
    int*   bpre      = (int*)  alloc(256 * 4);
    int*   csr_col   = (int*)  alloc((size_t)E * 4);        // 3.2 MB

    half1* xch = (half1*)d_out;   // fp16 xc lives in d_out during the loop

    hipMemsetAsync(zbase, 0, zbytes, stream);

    k_deg     <<<2048, 256, 0, stream>>>(row, deg_cnt, E);
    k_node    <<<128, 256, 0, stream>>>(x, y, mask, ylab, cls_cnt, mean_sum, N);
    k_blocksum<<<NB, 256, 0, stream>>>(deg_cnt, bsum, n4);
    k_scanmeta<<<1, 256, 0, stream>>>(bsum, bpre, NB, row_ptr + N,
                                      cls_cnt, cls_ptr, inv_cnt, mean_sum, meanv, N);
    k_fillptr <<<NB, 256, 0, stream>>>(deg_cnt, bpre, row_ptr, inv_deg, n4);
    k_fill    <<<2048, 256, 0, stream>>>(row, col, row_ptr, deg_cnt, csr_col,
                                         ylab, cls_ptr, cls_fill, cls_nodes, N, E);
    k_init    <<<1024, 256, 0, stream>>>(x, meanv, v0h, xch, N);
    // seed yv0 = Y^T v_0
    k_accum   <<<dim3(NC, 16), 256, 0, stream>>>(v0h, cls_ptr, cls_nodes, yv0);

    // primary: persistent cooperative loop (1024 blocks, guaranteed resident)
    int niter = 50;
    const half1* xch_c = xch;
    const float* invdeg_c = inv_deg;
    const int* rowptr_c = row_ptr;
    const int* csrcol_c = csr_col;
    const int* ylab_c = ylab;
    const float* invcnt_c = inv_cnt;
    void* kargs[] = {
        (void*)&v0h, (void*)&v1h, (void*)&xch_c, (void*)&invdeg_c,
        (void*)&rowptr_c, (void*)&csrcol_c, (void*)&ylab_c, (void*)&invcnt_c,
        (void*)&yv0, (void*)&yv1, (void*)&yv2, (void*)&N, (void*)&niter
    };
    hipError_t cerr = hipLaunchCooperativeKernel((void*)k_persist, dim3(1024),
                                                 dim3(256), kargs, 0, stream);
    if (cerr != hipSuccess) {
        // fallback: known-good 50-dispatch loop (R8, 1564 us)
        float* yv[3] = {yv0, yv1, yv2};
        int nblk = (N + 3) / 4;
        for (int t = 0; t < 50; ++t) {
            const half1* vc = (t & 1) ? v1h : v0h;
            half1*       vn = (t & 1) ? v0h : v1h;
            k_combine<<<nblk, 256, 0, stream>>>(vc, vn, xch, inv_deg, row_ptr,
                                                csr_col, ylab, yv[t % 3], inv_cnt,
                                                yv[(t + 1) % 3], yv[(t + 2) % 3], N);
        }
    }

    // 50 iters (even): final v in v0h
    int nblk2 = (N + 3) / 4;
    k_out<<<nblk2, 256, 0, stream>>>(v0h, weight, bias, (float*)d_out, N);
}

// Round 11
// 2501.248 us; speedup vs baseline: 5.0387x; 5.0387x over previous
//
#include <hip/hip_runtime.h>

#define NF 64
#define NC 40

typedef _Float16 half1;
typedef _Float16 half4 __attribute__((ext_vector_type(4)));
typedef _Float16 half8 __attribute__((ext_vector_type(8)));
typedef float    f32x4 __attribute__((ext_vector_type(4)));
typedef float    f32x8 __attribute__((ext_vector_type(8)));

// v layout: [2][N][32] fp16 — feature-half major; one half-row = 64B = 1 line.
// Loop runs as 50 separate dispatches (R10 lesson: cooperative grid.sync
// flushes per-XCD L2 every iteration -> 8x slowdown. Dispatch boundaries are
// cheap; cache residency is everything).

// ---------- setup kernels (run once per call) ----------

__global__ void k_deg(const int* __restrict__ row, int* __restrict__ deg_cnt, int E) {
    int stride = gridDim.x * blockDim.x;
    for (int e = blockIdx.x * blockDim.x + threadIdx.x; e < E; e += stride)
        atomicAdd(&deg_cnt[row[e]], 1);
}

__global__ void k_node(const float* __restrict__ x, const int* __restrict__ y,
                       const int* __restrict__ mask, int* __restrict__ ylab,
                       int* __restrict__ cls_cnt, float* __restrict__ mean_sum, int N) {
    __shared__ float lmean[NF];
    __shared__ int   lcls[NC];
    int t = threadIdx.x;
    if (t < NF) lmean[t] = 0.f;
    if (t < NC) lcls[t]  = 0;
    __syncthreads();
    int stride = gridDim.x * blockDim.x;
    const float4* x4 = (const float4*)x;
    int total4 = N * 16;
    f32x4 acc = {0.f, 0.f, 0.f, 0.f};
    for (int i = blockIdx.x * blockDim.x + t; i < total4; i += stride) {
        float4 v = x4[i];
        acc.x += v.x; acc.y += v.y; acc.z += v.z; acc.w += v.w;
    }
    int cbase = (t & 15) * 4;
    atomicAdd(&lmean[cbase + 0], acc.x);
    atomicAdd(&lmean[cbase + 1], acc.y);
    atomicAdd(&lmean[cbase + 2], acc.z);
    atomicAdd(&lmean[cbase + 3], acc.w);
    for (int i = blockIdx.x * blockDim.x + t; i < N; i += stride) {
        int lab = (mask[i] > 0) ? y[i] : -1;
        ylab[i] = lab;
        if (lab >= 0) atomicAdd(&lcls[lab], 1);
    }
    __syncthreads();
    if (t < NF) atomicAdd(&mean_sum[t], lmean[t]);
    if (t < NC) atomicAdd(&cls_cnt[t], lcls[t]);
}

// hierarchical scan of deg_cnt (N % 4 == 0; N=50000 -> n4=12500)
__global__ void __launch_bounds__(256) k_blocksum(const int* __restrict__ deg_cnt,
                                                  int* __restrict__ bsum, int n4) {
    __shared__ int red[256];
    int idx4 = blockIdx.x * 256 + threadIdx.x;
    int s = 0;
    if (idx4 < n4) {
        int4 d = ((const int4*)deg_cnt)[idx4];
        s = d.x + d.y + d.z + d.w;
    }
    red[threadIdx.x] = s;
    __syncthreads();
    for (int off = 128; off > 0; off >>= 1) {
        if (threadIdx.x < off) red[threadIdx.x] += red[threadIdx.x + off];
        __syncthreads();
    }
    if (threadIdx.x == 0) bsum[blockIdx.x] = red[0];
}

__global__ void k_scanmeta(const int* __restrict__ bsum, int* __restrict__ bpre, int NB,
                           int* __restrict__ row_ptr_last,
                           const int* __restrict__ cls_cnt, int* __restrict__ cls_ptr,
                           float* __restrict__ inv_cnt,
                           const float* __restrict__ mean_sum, float* __restrict__ meanv,
                           int N) {
    __shared__ int lds[256];
    int t = threadIdx.x;
    int v = (t < NB) ? bsum[t] : 0;
    lds[t] = v;
    __syncthreads();
    for (int off = 1; off < 256; off <<= 1) {
        int u = (t >= off) ? lds[t - off] : 0;
        __syncthreads();
        lds[t] += u;
        __syncthreads();
    }
    if (t < NB) bpre[t] = lds[t] - v;
    if (t == 255) *row_ptr_last = lds[255];
    if (t < NF) meanv[t] = mean_sum[t] * (1.f / (float)N);
    if (t == 0) {
        int s2 = 0;
        for (int c = 0; c < NC; ++c) {
            cls_ptr[c] = s2;
            int cc = cls_cnt[c];
            s2 += cc;
            inv_cnt[c] = 1.f / ((float)cc + 1e-8f);
        }
        cls_ptr[NC] = s2;
    }
}

__global__ void __launch_bounds__(256) k_fillptr(const int* __restrict__ deg_cnt,
                                                 const int* __restrict__ bpre,
                                                 int* __restrict__ row_ptr,
                                                 float* __restrict__ inv_deg, int n4) {
    __shared__ int lds[256];
    int t = threadIdx.x;
    int idx4 = blockIdx.x * 256 + t;
    int4 d = {0, 0, 0, 0};
    if (idx4 < n4) d = ((const int4*)deg_cnt)[idx4];
    int s = d.x + d.y + d.z + d.w;
    lds[t] = s;
    __syncthreads();
    for (int off = 1; off < 256; off <<= 1) {
        int u = (t >= off) ? lds[t - off] : 0;
        __syncthreads();
        lds[t] += u;
        __syncthreads();
    }
    if (idx4 < n4) {
        int base = bpre[blockIdx.x] + lds[t] - s;
        int4 rp;
        rp.x = base;
        rp.y = rp.x + d.x;
        rp.z = rp.y + d.y;
        rp.w = rp.z + d.z;
        ((int4*)row_ptr)[idx4] = rp;
        float4 id;
        id.x = 1.f / (float)(d.x + 1);
        id.y = 1.f / (float)(d.y + 1);
        id.z = 1.f / (float)(d.z + 1);
        id.w = 1.f / (float)(d.w + 1);
        ((float4*)inv_deg)[idx4] = id;
    }
}

// deg_cnt consumed as a countdown (re-zeroed by next call's memset).
__global__ void k_fill(const int* __restrict__ row, const int* __restrict__ col,
                       const int* __restrict__ row_ptr, int* __restrict__ deg_cnt,
                       int* __restrict__ csr_col, const int* __restrict__ ylab,
                       const int* __restrict__ cls_ptr, int* __restrict__ cls_fill,
                       int* __restrict__ cls_nodes, int N, int E) {
    int stride = gridDim.x * blockDim.x;
    for (int e = blockIdx.x * blockDim.x + threadIdx.x; e < E; e += stride) {
        int r = row[e];
        int d = atomicSub(&deg_cnt[r], 1);
        csr_col[row_ptr[r] + d - 1] = col[e];
    }
    for (int i = blockIdx.x * blockDim.x + threadIdx.x; i < N; i += stride) {
        int lab = ylab[i];
        if (lab >= 0) {
            int pos = cls_ptr[lab] + atomicAdd(&cls_fill[lab], 1);
            cls_nodes[pos] = i;
        }
    }
}

// v0h = xch = fp16(x - mean), written in split [2][N][32] layout
__global__ void k_init(const float* __restrict__ x, const float* __restrict__ meanv,
                       half1* __restrict__ v0h, half1* __restrict__ xch, int N) {
    int total = N * 16;                      // float4 count over x
    int stride = gridDim.x * blockDim.x;
    const float4* x4 = (const float4*)x;
    const float4* m4 = (const float4*)meanv;
    for (int idx = blockIdx.x * blockDim.x + threadIdx.x; idx < total; idx += stride) {
        float4 xv = x4[idx];
        float4 mv = m4[idx & 15];
        half4 h;
        h.x = (half1)(xv.x - mv.x);
        h.y = (half1)(xv.y - mv.y);
        h.z = (half1)(xv.z - mv.z);
        h.w = (half1)(xv.w - mv.w);
        int node = idx >> 4, j = idx & 15;
        int hf = j >> 3, q = j & 7;           // q: half4 chunk within the half-row
        long didx = ((long)hf * N + node) * 8 + q;
        ((half4*)v0h)[didx] = h;
        ((half4*)xch)[didx] = h;
    }
}

// seed yTv[0] = Y^T v_0 (split layout; correctness verified in R6)
__global__ void __launch_bounds__(256) k_accum(const half1* __restrict__ v,
                                               const int* __restrict__ cls_ptr,
                                               const int* __restrict__ cls_nodes,
                                               float* __restrict__ yTv, int N) {
    __shared__ float red[4 * NF];
    int c = blockIdx.x;
    int lane = threadIdx.x & 63;
    int w = threadIdx.x >> 6;
    int g = lane >> 4, q = lane & 15;
    int hf = q >> 3, qq = q & 7;
    int cbase = hf * 32 + qq * 4;
    int W = blockIdx.y * 4 + w;
    int cs = cls_ptr[c], ce = cls_ptr[c + 1];
    const half4* v4 = (const half4*)v;
    f32x4 acc = {0.f, 0.f, 0.f, 0.f};
    for (int p = cs + W * 4 + g; p < ce; p += 64 * 4) {
        int node = cls_nodes[p];
        acc += __builtin_convertvector(v4[((long)hf * N + node) * 8 + qq], f32x4);
    }
#pragma unroll
    for (int m = 16; m <= 32; m <<= 1) {
        acc.x += __shfl_xor(acc.x, m);
        acc.y += __shfl_xor(acc.y, m);
        acc.z += __shfl_xor(acc.z, m);
        acc.w += __shfl_xor(acc.w, m);
    }
    if (g == 0) {
        red[w * NF + cbase + 0] = acc.x;
        red[w * NF + cbase + 1] = acc.y;
        red[w * NF + cbase + 2] = acc.z;
        red[w * NF + cbase + 3] = acc.w;
    }
    __syncthreads();
    if (w == 0) {
        float s = red[0 * NF + lane] + red[1 * NF + lane] +
                  red[2 * NF + lane] + red[3 * NF + lane];
        atomicAdd(&yTv[c * NF + lane], s);
    }
}

// ---------- the per-iteration kernel (split-feature gather) ----------
// Half-row = 64B = 1 line. bid&7 in {0..3} -> half 0, {4..7} -> half 1:
// under round-robin block->XCD assignment each XCD's gather hot set is one
// 3.2MB half (< 4MB L2). Gather: 4 lanes x half8 per edge (one line);
// 16 edge streams x unroll 2. Self folded into stream 0.
// Epilogue: xor-reduce leaves each lane the full f32x8 of its chunk (lane&3);
// 8-way predicated select + ONE shfl redistributes so lanes 0..31 hold one
// feature each -> one coalesced 64B vn store + ONE wavefront-wide atomicAdd
// per labeled row-half (R6/R7 lesson: never per-lane loops of global atomics).
__global__ void __launch_bounds__(256) k_combine(
        const half1* __restrict__ v, half1* __restrict__ vn,
        const half1* __restrict__ xch, const float* __restrict__ inv_deg,
        const int* __restrict__ row_ptr, const int* __restrict__ csr_col,
        const int* __restrict__ ylab, const float* __restrict__ yv_cur,
        const float* __restrict__ inv_cnt, float* __restrict__ yv_acc,
        float* __restrict__ yv_zero, int N) {
    int bid = blockIdx.x;
    if (bid == 0) {
        for (int j = threadIdx.x; j < NC * NF; j += 256) yv_zero[j] = 0.f;
    }
    int r8 = bid & 7;
    int hf = r8 >> 2;                         // feature half
    int rowblk = (bid >> 3) * 4 + (r8 & 3);
    int lane = threadIdx.x & 63;
    int w = threadIdx.x >> 6;
    int i = rowblk * 4 + w;
    if (i >= N) return;
    int s = row_ptr[i], e = row_ptr[i + 1];
    int g = lane >> 2, q = lane & 3;          // 16 streams x 4 lanes (16B each)
    const half8* v8 = (const half8*)v;
    long vbase = (long)hf * N;
    f32x8 a0 = {0.f, 0.f, 0.f, 0.f, 0.f, 0.f, 0.f, 0.f};
    f32x8 a1 = {0.f, 0.f, 0.f, 0.f, 0.f, 0.f, 0.f, 0.f};
    if (g == 0)                               // self-loop folded into stream 0
        a0 = __builtin_convertvector(v8[(vbase + i) * 4 + q], f32x8);
    int p = s + g;
    for (; p + 16 < e; p += 32) {
        int c0 = csr_col[p];
        int c1 = csr_col[p + 16];
        half8 h0 = v8[(vbase + c0) * 4 + q];
        half8 h1 = v8[(vbase + c1) * 4 + q];
        a0 += __builtin_convertvector(h0, f32x8);
        a1 += __builtin_convertvector(h1, f32x8);
    }
    if (p < e) {
        int c0 = csr_col[p];
        a0 += __builtin_convertvector(v8[(vbase + c0) * 4 + q], f32x8);
    }
    a0 += a1;
    // reduce across the 16 streams (lane bits 2..5)
#pragma unroll
    for (int m = 4; m <= 32; m <<= 1) {
#pragma unroll
        for (int j = 0; j < 8; ++j)
            a0[j] += __shfl_xor(a0[j], m);
    }
    // redistribute: lane s (s<32) exports element (s>>2) of its chunk (s&3);
    // lane l<32 reads from source s = ((l&7)<<2) + (l>>3) -> feature f = l.
    int jj = (lane >> 2) & 7;
    float ex = a0[0];
#pragma unroll
    for (int j = 1; j < 8; ++j)
        if (jj == j) ex = a0[j];
    float gsum = __shfl(ex, ((lane & 7) << 2) + (lane >> 3), 64);
    if (lane < 32) {
        int f = hf * 32 + lane;               // global feature index
        float p1 = inv_deg[i] * gsum;         // self already folded in
        int lab = ylab[i];
        float p2 = (lab >= 0) ? yv_cur[lab * NF + f] * inv_cnt[lab] : 0.f;
        float base = (float)xch[(vbase + i) * 32 + lane];
        float res = 0.45f * p1 + 0.05f * p2 + 0.5f * base;
        vn[(vbase + i) * 32 + lane] = (half1)res;
        if (lab >= 0) atomicAdd(&yv_acc[lab * NF + f], res);
    }
}

// out = v @ W + bias  (v in split layout; writes f32 to d_out)
__global__ void __launch_bounds__(256) k_out(const half1* __restrict__ v,
                                             const float* __restrict__ Wm,
                                             const float* __restrict__ bias,
                                             float* __restrict__ out, int N) {
    __shared__ float Wl[NF * NF];
    for (int j = threadIdx.x; j < NF * NF; j += 256) Wl[j] = Wm[j];
    __syncthreads();
    int lane = threadIdx.x & 63;
    int w = threadIdx.x >> 6;
    int i = blockIdx.x * 4 + w;
    if (i >= N) return;
    int hf = lane >> 5, fi = lane & 31;
    float vr = (float)v[((long)hf * N + i) * 32 + fi];
    float acc = bias[lane];
#pragma unroll
    for (int k = 0; k < NF; ++k)
        acc += __shfl(vr, k, 64) * Wl[k * NF + lane];
    out[(long)i * NF + lane] = acc;
}

// ---------- launcher ----------

extern "C" void kernel_launch(void* const* d_in, const int* in_sizes, int n_in,
                              void* d_out, int out_size, void* d_ws, size_t ws_size,
                              hipStream_t stream) {
    const float* x      = (const float*)d_in[0];
    const float* weight = (const float*)d_in[1];
    const float* bias   = (const float*)d_in[2];
    const int*   row    = (const int*)d_in[3];
    const int*   col    = (const int*)d_in[4];
    const int*   y      = (const int*)d_in[5];
    const int*   mask   = (const int*)d_in[6];
    int N = in_sizes[0] / NF;
    int E = in_sizes[3];
    int n4 = N / 4;
    int NB = (n4 + 255) / 256;

    // ws (~17 MB). xc (fp16 split, 6.4 MB) lives in d_out — read-only during
    // the loop; k_out overwrites d_out only after the last k_combine finished.
    char* ws = (char*)d_ws;
    size_t off = 0;
    auto alloc = [&](size_t bytes) -> void* {
        void* p = ws + off;
        off = (off + bytes + 255) & ~(size_t)255;
        return p;
    };
    half1* v0h       = (half1*)alloc((size_t)N * NF * 2);   // 6.4 MB
    half1* v1h       = (half1*)alloc((size_t)N * NF * 2);   // 6.4 MB
    // zero region (one memset per call)
    char*  zbase     = ws + off;
    float* yv[3];
    yv[0]            = (float*)alloc(NC * NF * 4);
    yv[1]            = (float*)alloc(NC * NF * 4);
    yv[2]            = (float*)alloc(NC * NF * 4);
    int*   deg_cnt   = (int*)  alloc((size_t)N * 4);
    int*   cls_cnt   = (int*)  alloc(NC * 4);
    int*   cls_fill  = (int*)  alloc(NC * 4);
    float* mean_sum  = (float*)alloc(NF * 4);
    size_t zbytes = (size_t)((ws + off) - zbase);
    // setup-written, iteration-read
    float* meanv     = (float*)alloc(NF * 4);
    float* inv_deg   = (float*)alloc((size_t)N * 4);
    int*   row_ptr   = (int*)  alloc((size_t)(N + 1) * 4);
    int*   cls_ptr   = (int*)  alloc((NC + 1) * 4);
    float* inv_cnt   = (float*)alloc(NC * 4);
    int*   ylab      = (int*)  alloc((size_t)N * 4);
    int*   cls_nodes = (int*)  alloc((size_t)N * 4);
    int*   bsum      = (int*)  alloc(256 * 4);
    int*   bpre      = (int*)  alloc(256 * 4);
    int*   csr_col   = (int*)  alloc((size_t)E * 4);        // 3.2 MB

    half1* xch = (half1*)d_out;

    hipMemsetAsync(zbase, 0, zbytes, stream);

    k_deg     <<<2048, 256, 0, stream>>>(row, deg_cnt, E);
    k_node    <<<128, 256, 0, stream>>>(x, y, mask, ylab, cls_cnt, mean_sum, N);
    k_blocksum<<<NB, 256, 0, stream>>>(deg_cnt, bsum, n4);
    k_scanmeta<<<1, 256, 0, stream>>>(bsum, bpre, NB, row_ptr + N,
                                      cls_cnt, cls_ptr, inv_cnt, mean_sum, meanv, N);
    k_fillptr <<<NB, 256, 0, stream>>>(deg_cnt, bpre, row_ptr, inv_deg, n4);
    k_fill    <<<2048, 256, 0, stream>>>(row, col, row_ptr, deg_cnt, csr_col,
                                         ylab, cls_ptr, cls_fill, cls_nodes, N, E);
    k_init    <<<1024, 256, 0, stream>>>(x, meanv, v0h, xch, N);
    // seed yv[0] = Y^T v_0
    k_accum   <<<dim3(NC, 16), 256, 0, stream>>>(v0h, cls_ptr, cls_nodes, yv[0], N);

    int nblk = (N + 3) / 4;                    // 12500 row-blocks
    int grid = 8 * ((nblk + 3) / 4);           // 25000: both halves covered
    for (int t = 0; t < 50; ++t) {
        const half1* vc = (t & 1) ? v1h : v0h;
        half1*       vn = (t & 1) ? v0h : v1h;
        k_combine<<<grid, 256, 0, stream>>>(vc, vn, xch, inv_deg, row_ptr, csr_col,
                                            ylab, yv[t % 3], inv_cnt,
                                            yv[(t + 1) % 3], yv[(t + 2) % 3], N);
    }
    // 50 iters (even): final v in v0h
    k_out<<<nblk, 256, 0, stream>>>(v0h, weight, bias, (float*)d_out, N);
}

// Round 13
// 1537.757 us; speedup vs baseline: 8.1957x; 1.6266x over previous
//
#include <hip/hip_runtime.h>

#define NF 64
#define NC 40

typedef _Float16 half1;
typedef _Float16 half4 __attribute__((ext_vector_type(4)));
typedef _Float16 half8 __attribute__((ext_vector_type(8)));
typedef float    f32x4 __attribute__((ext_vector_type(4)));
typedef float    f32x8 __attribute__((ext_vector_type(8)));

// v layout: row-major [N][64] fp16. Loop = 50 separate dispatches (R10:
// cooperative grid.sync flushes per-XCD L2 -> 8x slower. R11: feature-split
// doubles index traffic -> 1.6x slower.)

// ---------- setup kernels (run once per call) ----------

__global__ void k_deg(const int* __restrict__ row, int* __restrict__ deg_cnt, int E) {
    int stride = gridDim.x * blockDim.x;
    for (int e = blockIdx.x * blockDim.x + threadIdx.x; e < E; e += stride)
        atomicAdd(&deg_cnt[row[e]], 1);
}

__global__ void k_node(const float* __restrict__ x, const int* __restrict__ y,
                       const int* __restrict__ mask, int* __restrict__ ylab,
                       int* __restrict__ cls_cnt, float* __restrict__ mean_sum, int N) {
    __shared__ float lmean[NF];
    __shared__ int   lcls[NC];
    int t = threadIdx.x;
    if (t < NF) lmean[t] = 0.f;
    if (t < NC) lcls[t]  = 0;
    __syncthreads();
    int stride = gridDim.x * blockDim.x;
    const float4* x4 = (const float4*)x;
    int total4 = N * 16;
    f32x4 acc = {0.f, 0.f, 0.f, 0.f};
    for (int i = blockIdx.x * blockDim.x + t; i < total4; i += stride) {
        float4 v = x4[i];
        acc.x += v.x; acc.y += v.y; acc.z += v.z; acc.w += v.w;
    }
    int cbase = (t & 15) * 4;
    atomicAdd(&lmean[cbase + 0], acc.x);
    atomicAdd(&lmean[cbase + 1], acc.y);
    atomicAdd(&lmean[cbase + 2], acc.z);
    atomicAdd(&lmean[cbase + 3], acc.w);
    for (int i = blockIdx.x * blockDim.x + t; i < N; i += stride) {
        int lab = (mask[i] > 0) ? y[i] : -1;
        ylab[i] = lab;
        if (lab >= 0) atomicAdd(&lcls[lab], 1);
    }
    __syncthreads();
    if (t < NF) atomicAdd(&mean_sum[t], lmean[t]);
    if (t < NC) atomicAdd(&cls_cnt[t], lcls[t]);
}

// hierarchical scan of deg_cnt (N % 4 == 0; N=50000 -> n4=12500)
__global__ void __launch_bounds__(256) k_blocksum(const int* __restrict__ deg_cnt,
                                                  int* __restrict__ bsum, int n4) {
    __shared__ int red[256];
    int idx4 = blockIdx.x * 256 + threadIdx.x;
    int s = 0;
    if (idx4 < n4) {
        int4 d = ((const int4*)deg_cnt)[idx4];
        s = d.x + d.y + d.z + d.w;
    }
    red[threadIdx.x] = s;
    __syncthreads();
    for (int off = 128; off > 0; off >>= 1) {
        if (threadIdx.x < off) red[threadIdx.x] += red[threadIdx.x + off];
        __syncthreads();
    }
    if (threadIdx.x == 0) bsum[blockIdx.x] = red[0];
}

__global__ void k_scanmeta(const int* __restrict__ bsum, int* __restrict__ bpre, int NB,
                           int* __restrict__ row_ptr_last,
                           const int* __restrict__ cls_cnt, int* __restrict__ cls_ptr,
                           float* __restrict__ inv_cnt,
                           const float* __restrict__ mean_sum, float* __restrict__ meanv,
                           int N) {
    __shared__ int lds[256];
    int t = threadIdx.x;
    int v = (t < NB) ? bsum[t] : 0;
    lds[t] = v;
    __syncthreads();
    for (int off = 1; off < 256; off <<= 1) {
        int u = (t >= off) ? lds[t - off] : 0;
        __syncthreads();
        lds[t] += u;
        __syncthreads();
    }
    if (t < NB) bpre[t] = lds[t] - v;
    if (t == 255) *row_ptr_last = lds[255];
    if (t < NF) meanv[t] = mean_sum[t] * (1.f / (float)N);
    if (t == 0) {
        int s2 = 0;
        for (int c = 0; c < NC; ++c) {
            cls_ptr[c] = s2;
            int cc = cls_cnt[c];
            s2 += cc;
            inv_cnt[c] = 1.f / ((float)cc + 1e-8f);
        }
        cls_ptr[NC] = s2;
    }
}

__global__ void __launch_bounds__(256) k_fillptr(const int* __restrict__ deg_cnt,
                                                 const int* __restrict__ bpre,
                                                 int* __restrict__ row_ptr,
                                                 float* __restrict__ inv_deg, int n4) {
    __shared__ int lds[256];
    int t = threadIdx.x;
    int idx4 = blockIdx.x * 256 + t;
    int4 d = {0, 0, 0, 0};
    if (idx4 < n4) d = ((const int4*)deg_cnt)[idx4];
    int s = d.x + d.y + d.z + d.w;
    lds[t] = s;
    __syncthreads();
    for (int off = 1; off < 256; off <<= 1) {
        int u = (t >= off) ? lds[t - off] : 0;
        __syncthreads();
        lds[t] += u;
        __syncthreads();
    }
    if (idx4 < n4) {
        int base = bpre[blockIdx.x] + lds[t] - s;
        int4 rp;
        rp.x = base;
        rp.y = rp.x + d.x;
        rp.z = rp.y + d.y;
        rp.w = rp.z + d.z;
        ((int4*)row_ptr)[idx4] = rp;
        float4 id;
        id.x = 1.f / (float)(d.x + 1);
        id.y = 1.f / (float)(d.y + 1);
        id.z = 1.f / (float)(d.z + 1);
        id.w = 1.f / (float)(d.w + 1);
        ((float4*)inv_deg)[idx4] = id;
    }
}

// deg_cnt consumed as a countdown (re-zeroed by next call's memset).
__global__ void k_fill(const int* __restrict__ row, const int* __restrict__ col,
                       const int* __restrict__ row_ptr, int* __restrict__ deg_cnt,
                       int* __restrict__ csr_col, const int* __restrict__ ylab,
                       const int* __restrict__ cls_ptr, int* __restrict__ cls_fill,
                       int* __restrict__ cls_nodes, int N, int E) {
    int stride = gridDim.x * blockDim.x;
    for (int e = blockIdx.x * blockDim.x + threadIdx.x; e < E; e += stride) {
        int r = row[e];
        int d = atomicSub(&deg_cnt[r], 1);
        csr_col[row_ptr[r] + d - 1] = col[e];
    }
    for (int i = blockIdx.x * blockDim.x + threadIdx.x; i < N; i += stride) {
        int lab = ylab[i];
        if (lab >= 0) {
            int pos = cls_ptr[lab] + atomicAdd(&cls_fill[lab], 1);
            cls_nodes[pos] = i;
        }
    }
}

// v0h = xch = fp16(x - mean)
__global__ void k_init(const float* __restrict__ x, const float* __restrict__ meanv,
                       half1* __restrict__ v0h, half1* __restrict__ xch, int N) {
    int total = N * 16;                      // half4 count
    int stride = gridDim.x * blockDim.x;
    const float4* x4 = (const float4*)x;
    const float4* m4 = (const float4*)meanv;
    for (int idx = blockIdx.x * blockDim.x + threadIdx.x; idx < total; idx += stride) {
        float4 xv = x4[idx];
        float4 mv = m4[idx & 15];
        half4 h;
        h.x = (half1)(xv.x - mv.x);
        h.y = (half1)(xv.y - mv.y);
        h.z = (half1)(xv.z - mv.z);
        h.w = (half1)(xv.w - mv.w);
        ((half4*)v0h)[idx] = h;
        ((half4*)xch)[idx] = h;
    }
}

// seed yTv[0] = Y^T v_0  (runs once; loop iterations produce yTv in k_combine)
__global__ void __launch_bounds__(256) k_accum(const half1* __restrict__ v,
                                               const int* __restrict__ cls_ptr,
                                               const int* __restrict__ cls_nodes,
                                               float* __restrict__ yTv) {
    __shared__ float red[4 * NF];
    int c = blockIdx.x;
    int lane = threadIdx.x & 63;
    int w = threadIdx.x >> 6;
    int g = lane >> 4, q = lane & 15;
    int W = blockIdx.y * 4 + w;
    int cs = cls_ptr[c], ce = cls_ptr[c + 1];
    const half4* v4 = (const half4*)v;
    f32x4 acc = {0.f, 0.f, 0.f, 0.f};
    for (int p = cs + W * 4 + g; p < ce; p += 64 * 4) {
        int node = cls_nodes[p];
        acc += __builtin_convertvector(v4[(long)node * 16 + q], f32x4);
    }
#pragma unroll
    for (int m = 16; m <= 32; m <<= 1) {
        acc.x += __shfl_xor(acc.x, m);
        acc.y += __shfl_xor(acc.y, m);
        acc.z += __shfl_xor(acc.z, m);
        acc.w += __shfl_xor(acc.w, m);
    }
    if (g == 0) {
        red[w * NF + q * 4 + 0] = acc.x;
        red[w * NF + q * 4 + 1] = acc.y;
        red[w * NF + q * 4 + 2] = acc.z;
        red[w * NF + q * 4 + 3] = acc.w;
    }
    __syncthreads();
    if (w == 0) {
        float s = red[0 * NF + lane] + red[1 * NF + lane] +
                  red[2 * NF + lane] + red[3 * NF + lane];
        atomicAdd(&yTv[c * NF + lane], s);
    }
}

// ---------- the per-iteration kernel ----------
// v_new[i] = 0.45*inv_deg[i]*(v[i]+sum_nbr v) + 0.05*p2[i] + 0.5*xc[i]
// Index preload: ONE coalesced 64-wide load covers the row's first 64 edge
// indices; __shfl distributes each index to its 8-lane gather group
// (replaces 8x-replicated scattered scalar index loads with 4 coalesced
// lines + register-speed shfl). Edge coverage identical to R8.
// SELF-ROW IS ADDED IN THE EPILOGUE ONLY (R12 bug: folding it into stream 0
// while also adding selfv in the epilogue double-counted v[i]).
// Epilogue: all 64 lanes finalize one feature -> ONE wavefront-wide atomic
// per labeled row (R6/R7 lesson: never per-lane loops of global atomics).
__global__ void __launch_bounds__(256) k_combine(
        const half1* __restrict__ v, half1* __restrict__ vn,
        const half1* __restrict__ xch, const float* __restrict__ inv_deg,
        const int* __restrict__ row_ptr, const int* __restrict__ csr_col,
        const int* __restrict__ ylab, const float* __restrict__ yv_cur,
        const float* __restrict__ inv_cnt, float* __restrict__ yv_acc,
        float* __restrict__ yv_zero, int N) {
    int lane = threadIdx.x & 63;
    int w = threadIdx.x >> 6;
    int i = blockIdx.x * 4 + w;
    if (blockIdx.x == 0) {
        for (int j = threadIdx.x; j < NC * NF; j += 256) yv_zero[j] = 0.f;
    }
    if (i >= N) return;
    int s = row_ptr[i], e = row_ptr[i + 1];
    int nd = e - s;                           // neighbor count (excl. self)
    int g = lane >> 3, q = lane & 7;          // 8 streams x 8 lanes (16B each)
    const half8* v8 = (const half8*)v;
    // coalesced index preload: lane l holds csr_col[s+l] (first 64 edges)
    int idx = (lane < nd) ? csr_col[s + lane] : 0;
    f32x8 a0 = {0.f, 0.f, 0.f, 0.f, 0.f, 0.f, 0.f, 0.f};
    f32x8 a1 = {0.f, 0.f, 0.f, 0.f, 0.f, 0.f, 0.f, 0.f};
    int ndc = nd < 64 ? nd : 64;
    for (int r = 0; r < ndc; r += 16) {       // two 8-edge rounds per pass
        int s0 = g + r;
        int s1 = s0 + 8;
        int c0 = __shfl(idx, s0, 64);         // register-speed index broadcast
        int c1 = __shfl(idx, s1, 64);
        if (s0 < ndc)
            a0 += __builtin_convertvector(v8[(long)c0 * 8 + q], f32x8);
        if (s1 < ndc)
            a1 += __builtin_convertvector(v8[(long)c1 * 8 + q], f32x8);
    }
    // rare tail: degree > 64 (P ~ 0 for Poisson(16), but must be correct)
    for (int p = s + 64 + g; p < e; p += 8) {
        int c0 = csr_col[p];
        a0 += __builtin_convertvector(v8[(long)c0 * 8 + q], f32x8);
    }
    a0 += a1;
    // sum across the 8 streams (lane bits 3..5)
#pragma unroll
    for (int m = 8; m <= 32; m <<= 1) {
#pragma unroll
        for (int j = 0; j < 8; ++j)
            a0[j] += __shfl_xor(a0[j], m);
    }
    int f = q * 8 + g;                        // this lane finalizes feature f
    float gsum = a0[g];
    float selfv = (float)v[(long)i * NF + f];
    float p1 = inv_deg[i] * (gsum + selfv);
    int lab = ylab[i];
    float p2 = (lab >= 0) ? yv_cur[lab * NF + f] * inv_cnt[lab] : 0.f;
    float base = (float)xch[(long)i * NF + f];
    float res = 0.45f * p1 + 0.05f * p2 + 0.5f * base;
    vn[(long)i * NF + f] = (half1)res;
    if (lab >= 0) atomicAdd(&yv_acc[lab * NF + f], res);
}

// out = v @ W + bias  (reads fp16 v from ws, writes f32 to d_out)
__global__ void __launch_bounds__(256) k_out(const half1* __restrict__ v,
                                             const float* __restrict__ Wm,
                                             const float* __restrict__ bias,
                                             float* __restrict__ out, int N) {
    __shared__ float Wl[NF * NF];
    for (int j = threadIdx.x; j < NF * NF; j += 256) Wl[j] = Wm[j];
    __syncthreads();
    int lane = threadIdx.x & 63;
    int w = threadIdx.x >> 6;
    int i = blockIdx.x * 4 + w;
    if (i >= N) return;
    float vr = (float)v[(long)i * NF + lane];
    float acc = bias[lane];
#pragma unroll
    for (int k = 0; k < NF; ++k)
        acc += __shfl(vr, k, 64) * Wl[k * NF + lane];
    out[(long)i * NF + lane] = acc;
}

// ---------- launcher ----------

extern "C" void kernel_launch(void* const* d_in, const int* in_sizes, int n_in,
                              void* d_out, int out_size, void* d_ws, size_t ws_size,
                              hipStream_t stream) {
    const float* x      = (const float*)d_in[0];
    const float* weight = (const float*)d_in[1];
    const float* bias   = (const float*)d_in[2];
    const int*   row    = (const int*)d_in[3];
    const int*   col    = (const int*)d_in[4];
    const int*   y      = (const int*)d_in[5];
    const int*   mask   = (const int*)d_in[6];
    int N = in_sizes[0] / NF;
    int E = in_sizes[3];
    int n4 = N / 4;
    int NB = (n4 + 255) / 256;

    // ws (~17 MB). xc (fp16, 6.4 MB) lives in d_out — read-only during the
    // loop; k_out overwrites d_out only after the last k_combine finished.
    char* ws = (char*)d_ws;
    size_t off = 0;
    auto alloc = [&](size_t bytes) -> void* {
        void* p = ws + off;
        off = (off + bytes + 255) & ~(size_t)255;
        return p;
    };
    half1* v0h       = (half1*)alloc((size_t)N * NF * 2);   // 6.4 MB
    half1* v1h       = (half1*)alloc((size_t)N * NF * 2);   // 6.4 MB
    // zero region (one memset per call)
    char*  zbase     = ws + off;
    float* yv[3];
    yv[0]            = (float*)alloc(NC * NF * 4);
    yv[1]            = (float*)alloc(NC * NF * 4);
    yv[2]            = (float*)alloc(NC * NF * 4);
    int*   deg_cnt   = (int*)  alloc((size_t)N * 4);
    int*   cls_cnt   = (int*)  alloc(NC * 4);
    int*   cls_fill  = (int*)  alloc(NC * 4);
    float* mean_sum  = (float*)alloc(NF * 4);
    size_t zbytes = (size_t)((ws + off) - zbase);
    // setup-written, iteration-read
    float* meanv     = (float*)alloc(NF * 4);
    float* inv_deg   = (float*)alloc((size_t)N * 4);
    int*   row_ptr   = (int*)  alloc((size_t)(N + 1) * 4);
    int*   cls_ptr   = (int*)  alloc((NC + 1) * 4);
    float* inv_cnt   = (float*)alloc(NC * 4);
    int*   ylab      = (int*)  alloc((size_t)N * 4);
    int*   cls_nodes = (int*)  alloc((size_t)N * 4);
    int*   bsum      = (int*)  alloc(256 * 4);
    int*   bpre      = (int*)  alloc(256 * 4);
    int*   csr_col   = (int*)  alloc((size_t)E * 4);        // 3.2 MB

    half1* xch = (half1*)d_out;

    hipMemsetAsync(zbase, 0, zbytes, stream);

    k_deg     <<<2048, 256, 0, stream>>>(row, deg_cnt, E);
    k_node    <<<128, 256, 0, stream>>>(x, y, mask, ylab, cls_cnt, mean_sum, N);
    k_blocksum<<<NB, 256, 0, stream>>>(deg_cnt, bsum, n4);
    k_scanmeta<<<1, 256, 0, stream>>>(bsum, bpre, NB, row_ptr + N,
                                      cls_cnt, cls_ptr, inv_cnt, mean_sum, meanv, N);
    k_fillptr <<<NB, 256, 0, stream>>>(deg_cnt, bpre, row_ptr, inv_deg, n4);
    k_fill    <<<2048, 256, 0, stream>>>(row, col, row_ptr, deg_cnt, csr_col,
                                         ylab, cls_ptr, cls_fill, cls_nodes, N, E);
    k_init    <<<1024, 256, 0, stream>>>(x, meanv, v0h, xch, N);
    // seed yv[0] = Y^T v_0
    k_accum   <<<dim3(NC, 16), 256, 0, stream>>>(v0h, cls_ptr, cls_nodes, yv[0]);

    int nblk = (N + 3) / 4;
    for (int t = 0; t < 50; ++t) {
        const half1* vc = (t & 1) ? v1h : v0h;
        half1*       vn = (t & 1) ? v0h : v1h;
        k_combine<<<nblk, 256, 0, stream>>>(vc, vn, xch, inv_deg, row_ptr, csr_col,
                                            ylab, yv[t % 3], inv_cnt,
                                            yv[(t + 1) % 3], yv[(t + 2) % 3], N);
    }
    // 50 iters (even): final v in v0h
    k_out<<<nblk, 256, 0, stream>>>(v0h, weight, bias, (float*)d_out, N);
}